// Round 8
// baseline (258.162 us; speedup 1.0000x reference)
//
#include <hip/hip_runtime.h>
#include <math.h>

#define Hh 128
#define Ww 128
#define Dd 256
#define Bb 4
#define HW (Hh*Ww)        // 16384
#define NPIX (Bb*HW)      // 65536
#define WP 132            // padded width/height (2-px zero ring)

typedef __attribute__((ext_vector_type(8))) short s16x8;   // 8 bf16 (4 VGPRs)
typedef __attribute__((ext_vector_type(4))) float f32x4;

__device__ __forceinline__ unsigned short f2bf(float f) {
    unsigned u = __float_as_uint(f);
    u += 0x7FFF + ((u >> 16) & 1);
    return (unsigned short)(u >> 16);
}

__device__ __forceinline__ float gelu_exact(float v) {
    return 0.5f * v * (1.0f + erff(v * 0.70710678118654752f));
}

// ---------- K0: zero padded activation buffers + transpose conv weights ----------
#define ZGRAN 1115136
__global__ __launch_bounds__(256) void setup_fill(const float* __restrict__ w0,
                                                  const float* __restrict__ w1,
                                                  const float* __restrict__ w2,
                                                  unsigned short* __restrict__ wb0,
                                                  unsigned short* __restrict__ wb1,
                                                  unsigned short* __restrict__ wb2,
                                                  uint4* __restrict__ zbase) {
    int t = blockIdx.x * 256 + threadIdx.x;
    if (t < ZGRAN) {
        zbase[t] = (uint4){0, 0, 0, 0};
        return;
    }
    int u = t - ZGRAN;
    if (u < 51200) {
        int tap = u >> 11; int r = u & 2047; int n = r >> 6; int k = r & 63;
        wb0[u] = (k < 52) ? f2bf(w0[n * 1300 + k * 25 + tap]) : (unsigned short)0;
    } else if (u < 76800) {
        int v = u - 51200; int tap = v >> 10; int r = v & 1023; int n = r >> 5; int k = r & 31;
        wb1[v] = f2bf(w1[n * 800 + k * 25 + tap]);
    } else if (u < 89600) {
        int v = u - 76800; int tap = v >> 9; int r = v & 511; int n = r >> 5; int k = r & 31;
        wb2[v] = (n < 2) ? f2bf(w2[n * 800 + k * 25 + tap]) : (unsigned short)0;
    }
}

// ---------- K1: fused normalize, 16-lane groups (4 pixels/wave) ----------
__global__ __launch_bounds__(256) void norm_fused(const float* __restrict__ vis,
                                                  const float* __restrict__ rub,
                                                  unsigned short* __restrict__ kn,
                                                  unsigned short* __restrict__ qn) {
    int tid = threadIdx.x;
    int g16 = tid >> 4, l = tid & 15;
    int blk = blockIdx.x;
    if (blk < 4096) {
        int pix = blk * 16 + g16;
        const float* base = vis + (size_t)pix * Dd + l * 4;
        float4 v[4];
#pragma unroll
        for (int i = 0; i < 4; i++) v[i] = *(const float4*)(base + i * 64);
        float ss = 0.f;
#pragma unroll
        for (int i = 0; i < 4; i++)
            ss += v[i].x * v[i].x + v[i].y * v[i].y + v[i].z * v[i].z + v[i].w * v[i].w;
#pragma unroll
        for (int o = 1; o <= 8; o <<= 1) ss += __shfl_xor(ss, o, 64);
        float inv = __builtin_amdgcn_rsqf(fmaxf(ss, 1e-24f));
        unsigned short* op = kn + (size_t)pix * Dd + l * 4;
#pragma unroll
        for (int i = 0; i < 4; i++) {
            ushort4 o4;
            o4.x = f2bf(v[i].x * inv); o4.y = f2bf(v[i].y * inv);
            o4.z = f2bf(v[i].z * inv); o4.w = f2bf(v[i].w * inv);
            *(ushort4*)(op + i * 64) = o4;
        }
    } else {
        int pix = (blk - 4096) * 16 + g16;
        int b = pix >> 14; int yx = pix & 16383; int y = yx >> 7; int x = yx & 127;
        float sy = 0.5f * y - 0.25f;
        float sx = 0.5f * x - 0.25f;
        int y0 = (int)floorf(sy); float fy = sy - (float)y0;
        int x0 = (int)floorf(sx); float fx = sx - (float)x0;
        int y0c = max(y0, 0), y1c = min(y0 + 1, 63);
        int x0c = max(x0, 0), x1c = min(x0 + 1, 63);
        const float* base = rub + (size_t)b * 4096 * Dd + l * 4;
        const float* p00 = base + (size_t)(y0c * 64 + x0c) * Dd;
        const float* p01 = base + (size_t)(y0c * 64 + x1c) * Dd;
        const float* p10 = base + (size_t)(y1c * 64 + x0c) * Dd;
        const float* p11 = base + (size_t)(y1c * 64 + x1c) * Dd;
        float w00 = (1.f - fy) * (1.f - fx), w01 = (1.f - fy) * fx;
        float w10 = fy * (1.f - fx), w11 = fy * fx;
        float4 bv[4];
        float ss = 0.f;
#pragma unroll
        for (int i = 0; i < 4; i++) {
            float4 a = *(const float4*)(p00 + i * 64);
            float4 b1 = *(const float4*)(p01 + i * 64);
            float4 c = *(const float4*)(p10 + i * 64);
            float4 d = *(const float4*)(p11 + i * 64);
            float4 v;
            v.x = w00 * a.x + w01 * b1.x + w10 * c.x + w11 * d.x;
            v.y = w00 * a.y + w01 * b1.y + w10 * c.y + w11 * d.y;
            v.z = w00 * a.z + w01 * b1.z + w10 * c.z + w11 * d.z;
            v.w = w00 * a.w + w01 * b1.w + w10 * c.w + w11 * d.w;
            bv[i] = v;
            ss += v.x * v.x + v.y * v.y + v.z * v.z + v.w * v.w;
        }
#pragma unroll
        for (int o = 1; o <= 8; o <<= 1) ss += __shfl_xor(ss, o, 64);
        float inv = __builtin_amdgcn_rsqf(fmaxf(ss, 1e-24f));
        unsigned short* op = qn + (size_t)pix * Dd + l * 4;
#pragma unroll
        for (int i = 0; i < 4; i++) {
            ushort4 o4;
            o4.x = f2bf(bv[i].x * inv); o4.y = f2bf(bv[i].y * inv);
            o4.z = f2bf(bv[i].z * inv); o4.w = f2bf(bv[i].w * inv);
            *(ushort4*)(op + i * 64) = o4;
        }
    }
}

// ---------- K2: 8x16-tile LDS corr + shuffle softmax; 512 thr, 2 blocks/CU ----------
// neighborhood 14x22 = 308 px staged per 32-ch chunk (8 chunks)
__global__ __launch_bounds__(512, 4) void corr_block(const unsigned short* __restrict__ qn,
                                                     const unsigned short* __restrict__ kn,
                                                     const float* __restrict__ log_temp,
                                                     unsigned short* __restrict__ xb,
                                                     float* __restrict__ out) {
    __shared__ char smem[308 * 5 * 16];   // 24640 B
    int tid = threadIdx.x;
    int wid = tid >> 6, lane = tid & 63, l15 = lane & 15, quad = lane >> 4;
    // XCD swizzle: r=blk&7 -> (image, x-half); t=blk>>3 -> (tile-row, tile-col-in-half)
    int blk = blockIdx.x;
    int r = blk & 7, t = blk >> 3;
    int b = r >> 1, xh = r & 1;
    int ty = t & 15, txl = t >> 4;
    int y0 = ty * 8, x0 = (xh * 4 + txl) * 16;
    int y = y0 + wid;

    // staging: 1232 granules over 512 threads (3 rounds)
    const unsigned short* srcs[3]; int dsts[3]; bool have[3];
#pragma unroll
    for (int s = 0; s < 3; s++) {
        int g = s * 512 + tid;
        have[s] = (g < 1232);
        int gc = have[s] ? g : 1231;
        int px = gc >> 2, sub = gc & 3;
        int ry = px / 22, rx = px - ry * 22;
        int yy = min(max(y0 - 3 + ry, 0), 127);
        int xx = min(max(x0 - 3 + rx, 0), 127);
        srcs[s] = kn + ((size_t)(b << 14) + yy * 128 + xx) * 256 + sub * 8;
        dsts[s] = (px * 5 + sub) * 16;
    }
    int lpixoff[10];
#pragma unroll
    for (int f = 0; f < 10; f++) {
        int p = min(f * 16 + l15, 153);
        int pr = p / 22, pc = p - pr * 22;
        lpixoff[f] = (((wid + pr) * 22 + pc) * 5 + quad) * 16;
    }
    const unsigned short* aptr = qn + ((size_t)(b << 14) + y * 128 + x0 + l15) * 256 + quad * 8;

    f32x4 acc[10];
#pragma unroll
    for (int f = 0; f < 10; f++) acc[f] = (f32x4){0.f, 0.f, 0.f, 0.f};

    uint4 v[3];
#pragma unroll
    for (int s = 0; s < 3; s++) v[s] = *(const uint4*)srcs[s];
    s16x8 an = *(const s16x8*)aptr;
    for (int c = 0; c < 8; c++) {
        uint4 w[3];
#pragma unroll
        for (int s = 0; s < 3; s++) w[s] = v[s];
        s16x8 a = an;
        if (c < 7) {
#pragma unroll
            for (int s = 0; s < 3; s++) v[s] = *(const uint4*)(srcs[s] + (c + 1) * 32);
            an = *(const s16x8*)(aptr + (c + 1) * 32);
        }
        __syncthreads();
#pragma unroll
        for (int s = 0; s < 3; s++)
            if (have[s]) *(uint4*)(smem + dsts[s]) = w[s];
        __syncthreads();
#pragma unroll
        for (int f = 0; f < 10; f++) {
            s16x8 bf = *(const s16x8*)(smem + lpixoff[f]);
            acc[f] = __builtin_amdgcn_mfma_f32_16x16x32_bf16(a, bf, acc[f], 0, 0, 0);
        }
    }

    // ---- softmax epilogue (per-wave row, 4 px per quad-group) ----
    float inv_temp = expf(-log_temp[0]);
    float vmax[4] = {-1e30f, -1e30f, -1e30f, -1e30f};
#pragma unroll
    for (int f = 0; f < 10; f++) {
        int n = f * 16 + l15;
        if (n <= 153) {
            int dy = n / 22 - 3;
            int rx = n - (dy + 3) * 22;
#pragma unroll
            for (int i = 0; i < 4; i++) {
                int m = quad * 4 + i;
                int dx = rx - m - 3;
                if ((unsigned)(dx + 3) <= 6u) vmax[i] = fmaxf(vmax[i], acc[f][i]);
            }
        }
    }
#pragma unroll
    for (int o = 1; o <= 8; o <<= 1) {
#pragma unroll
        for (int i = 0; i < 4; i++) vmax[i] = fmaxf(vmax[i], __shfl_xor(vmax[i], o, 64));
    }
    float se[4] = {0, 0, 0, 0}, sey[4] = {0, 0, 0, 0}, sex[4] = {0, 0, 0, 0}, emax[4] = {0, 0, 0, 0};
    unsigned short* xrow = xb + ((size_t)(b * WP + y + 2) * WP + x0 + 2) * 64;
#pragma unroll
    for (int f = 0; f < 10; f++) {
        int n = f * 16 + l15;
        if (n <= 153) {
            int dy = n / 22 - 3;
            int rx = n - (dy + 3) * 22;
#pragma unroll
            for (int i = 0; i < 4; i++) {
                int m = quad * 4 + i;
                int dx = rx - m - 3;
                if ((unsigned)(dx + 3) <= 6u) {
                    float vv = acc[f][i];
                    float e = expf((vv - vmax[i]) * inv_temp);
                    se[i] += e;
                    sey[i] += e * (float)dy;
                    sex[i] += e * (float)dx;
                    emax[i] = fmaxf(emax[i], e);
                    xrow[(size_t)m * 64 + 2 + (dy + 3) * 7 + (dx + 3)] = f2bf(vv);
                }
            }
        }
    }
#pragma unroll
    for (int o = 1; o <= 8; o <<= 1) {
#pragma unroll
        for (int i = 0; i < 4; i++) {
            se[i] += __shfl_xor(se[i], o, 64);
            sey[i] += __shfl_xor(sey[i], o, 64);
            sex[i] += __shfl_xor(sex[i], o, 64);
            emax[i] = fmaxf(emax[i], __shfl_xor(emax[i], o, 64));
        }
    }
    if (l15 == 0) {
#pragma unroll
        for (int i = 0; i < 4; i++) {
            int m = quad * 4 + i;
            float inv_se = 1.0f / se[i];
            float dyv = sey[i] * inv_se, dxv = sex[i] * inv_se, conf = emax[i] * inv_se;
            unsigned short* xp = xrow + (size_t)m * 64;
            xp[0] = f2bf(dyv); xp[1] = f2bf(dxv); xp[51] = f2bf(conf);
            float* op = out + (size_t)b * 5 * HW + y * 128 + x0 + m;
            op[2 * HW] = dyv; op[3 * HW] = dxv; op[4 * HW] = conf;
        }
    }
}

// ---------- 8x16-tile MFMA conv: 256 thr / 4 waves, wave = 2 rows; 4 blocks/CU ----------
// A halo 12x20 = 240 px per 32-ch chunk
template <int KS, int OC, bool GELU>
__global__ __launch_bounds__(256, 4) void conv_tile(const unsigned short* __restrict__ in,
                                                    const unsigned short* __restrict__ wb,
                                                    const float* __restrict__ bias,
                                                    unsigned short* __restrict__ outp) {
    constexpr int ICP = KS * 32;
    constexpr int NF = OC / 16;
    constexpr int ABYTES = 240 * 5 * 16;        // 19200
    constexpr int WBYTES = 5 * OC * 5 * 16;
    __shared__ char smem[ABYTES + WBYTES];
    int tid = threadIdx.x;
    int wv = tid >> 6, lane = tid & 63, l15 = lane & 15, quad = lane >> 4;
    int blk = blockIdx.x;
    int r = blk & 7, t = blk >> 3;
    int b = r >> 1, xh = r & 1;
    int ty = t & 15, txl = t >> 4;
    int y0 = ty * 8, x0 = (xh * 4 + txl) * 16;

    f32x4 acc[2][NF];
#pragma unroll
    for (int rr = 0; rr < 2; rr++)
#pragma unroll
        for (int g = 0; g < NF; g++) acc[rr][g] = (f32x4){0.f, 0.f, 0.f, 0.f};

    for (int ks = 0; ks < KS; ks++) {
        __syncthreads();
        // stage A: 240 px x 4 granules = 960 granules, 4 rounds of 256
#pragma unroll
        for (int i = 0; i < 4; i++) {
            int g = i * 256 + tid;
            if (g < 960) {
                int px = g >> 2, sub = g & 3;
                int rw = px / 20, cc = px - rw * 20;
                *(uint4*)(smem + (px * 5 + sub) * 16) =
                    *(const uint4*)(in + ((size_t)(b * WP + y0 + rw) * WP + x0 + cc) * ICP + ks * 32 + sub * 8);
            }
        }
        for (int ky = 0; ky < 5; ky++) {
            if (ky > 0) __syncthreads();
            constexpr int WGR = 5 * OC * 4;
#pragma unroll
            for (int i = 0; i < (WGR + 255) / 256; i++) {
                int g = i * 256 + tid;
                if (g < WGR) {
                    int nl = g >> 2, sub = g & 3;
                    *(uint4*)(smem + ABYTES + (nl * 5 + sub) * 16) =
                        *(const uint4*)(wb + ((size_t)(ky * 5 * OC) + nl) * ICP + ks * 32 + sub * 8);
                }
            }
            __syncthreads();
#pragma unroll
            for (int kx = 0; kx < 5; kx++) {
                s16x8 a0 = *(const s16x8*)(smem + (((2 * wv + 0 + ky) * 20 + l15 + kx) * 5 + quad) * 16);
                s16x8 a1 = *(const s16x8*)(smem + (((2 * wv + 1 + ky) * 20 + l15 + kx) * 5 + quad) * 16);
#pragma unroll
                for (int g = 0; g < NF; g++) {
                    s16x8 bf = *(const s16x8*)(smem + ABYTES + ((kx * OC + g * 16 + l15) * 5 + quad) * 16);
                    acc[0][g] = __builtin_amdgcn_mfma_f32_16x16x32_bf16(a0, bf, acc[0][g], 0, 0, 0);
                    acc[1][g] = __builtin_amdgcn_mfma_f32_16x16x32_bf16(a1, bf, acc[1][g], 0, 0, 0);
                }
            }
        }
    }
#pragma unroll
    for (int rr = 0; rr < 2; rr++) {
        size_t orow = ((size_t)(b * WP + y0 + 2 * wv + rr + 2) * WP + x0 + 2) * OC;
#pragma unroll
        for (int g = 0; g < NF; g++) {
            float bv = bias[g * 16 + l15];
#pragma unroll
            for (int r4 = 0; r4 < 4; r4++) {
                int m = quad * 4 + r4;
                float vv = acc[rr][g][r4] + bv;
                if (GELU) vv = gelu_exact(vv);
                outp[orow + (size_t)m * OC + g * 16 + l15] = f2bf(vv);
            }
        }
    }
}

// ---------- final conv (32->2, OC padded 16), 8x16 tile + residual + sky scaling ----------
__global__ __launch_bounds__(256, 4) void conv_final_tile(const unsigned short* __restrict__ in,
                                                          const unsigned short* __restrict__ wb,
                                                          const float* __restrict__ bias,
                                                          float* __restrict__ out) {
    constexpr int ICP = 32, OC = 16;
    constexpr int ABYTES = 240 * 5 * 16;      // 19200
    constexpr int WBYTES = 5 * OC * 5 * 16;   // 6400
    __shared__ char smem[ABYTES + WBYTES];
    int tid = threadIdx.x;
    int wv = tid >> 6, lane = tid & 63, l15 = lane & 15, quad = lane >> 4;
    int blk = blockIdx.x;
    int r = blk & 7, t = blk >> 3;
    int b = r >> 1, xh = r & 1;
    int ty = t & 15, txl = t >> 4;
    int y0 = ty * 8, x0 = (xh * 4 + txl) * 16;

    f32x4 acc[2];
    acc[0] = (f32x4){0.f, 0.f, 0.f, 0.f};
    acc[1] = (f32x4){0.f, 0.f, 0.f, 0.f};
#pragma unroll
    for (int i = 0; i < 4; i++) {
        int g = i * 256 + tid;
        if (g < 960) {
            int px = g >> 2, sub = g & 3;
            int rw = px / 20, cc = px - rw * 20;
            *(uint4*)(smem + (px * 5 + sub) * 16) =
                *(const uint4*)(in + ((size_t)(b * WP + y0 + rw) * WP + x0 + cc) * ICP + sub * 8);
        }
    }
    for (int ky = 0; ky < 5; ky++) {
        if (ky > 0) __syncthreads();
        constexpr int WGR = 5 * OC * 4;   // 320
#pragma unroll
        for (int i = 0; i < 2; i++) {
            int g = i * 256 + tid;
            if (g < WGR) {
                int nl = g >> 2, sub = g & 3;
                *(uint4*)(smem + ABYTES + (nl * 5 + sub) * 16) =
                    *(const uint4*)(wb + ((size_t)(ky * 5 * OC) + nl) * ICP + sub * 8);
            }
        }
        __syncthreads();
#pragma unroll
        for (int kx = 0; kx < 5; kx++) {
            s16x8 a0 = *(const s16x8*)(smem + (((2 * wv + 0 + ky) * 20 + l15 + kx) * 5 + quad) * 16);
            s16x8 a1 = *(const s16x8*)(smem + (((2 * wv + 1 + ky) * 20 + l15 + kx) * 5 + quad) * 16);
            s16x8 bf = *(const s16x8*)(smem + ABYTES + ((kx * OC + l15) * 5 + quad) * 16);
            acc[0] = __builtin_amdgcn_mfma_f32_16x16x32_bf16(a0, bf, acc[0], 0, 0, 0);
            acc[1] = __builtin_amdgcn_mfma_f32_16x16x32_bf16(a1, bf, acc[1], 0, 0, 0);
        }
    }
    if (l15 < 2) {
        float bv = bias[l15];
#pragma unroll
        for (int rr = 0; rr < 2; rr++) {
#pragma unroll
            for (int r4 = 0; r4 < 4; r4++) {
                int m = quad * 4 + r4;
                size_t p5 = (size_t)b * 5 * HW + (y0 + 2 * wv + rr) * Ww + x0 + m;
                float a = acc[rr][r4] + bv;
                if (l15 == 0) {
                    float dyv = out[p5 + 2 * HW];
                    out[p5 + HW] = (dyv + a) * 1.6f;   // ddec
                } else {
                    float dxv = out[p5 + 3 * HW];
                    out[p5] = (dxv + a) * 1.6f;        // dra
                }
            }
        }
    }
}

extern "C" void kernel_launch(void* const* d_in, const int* in_sizes, int n_in,
                              void* d_out, int out_size, void* d_ws, size_t ws_size,
                              hipStream_t stream) {
    const float* rub = (const float*)d_in[0];
    const float* vis = (const float*)d_in[1];
    const float* w0 = (const float*)d_in[2];
    const float* b0 = (const float*)d_in[3];
    const float* w1 = (const float*)d_in[4];
    const float* b1 = (const float*)d_in[5];
    const float* w2 = (const float*)d_in[6];
    const float* b2 = (const float*)d_in[7];
    const float* log_temp = (const float*)d_in[8];
    float* out = (float*)d_out;

    char* ws = (char*)d_ws;
    size_t off = 0;
    const size_t PADPIX = (size_t)Bb * WP * WP;     // 69,696
    unsigned short* kn = (unsigned short*)(ws + off); off += (size_t)NPIX * Dd * 2;
    unsigned short* qn = (unsigned short*)(ws + off); off += (size_t)NPIX * Dd * 2;
    unsigned short* xbp = (unsigned short*)(ws + off); off += PADPIX * 64 * 2;   // contiguous
    unsigned short* h1p = (unsigned short*)(ws + off); off += PADPIX * 32 * 2;   //  zero
    unsigned short* h2p = (unsigned short*)(ws + off); off += PADPIX * 32 * 2;   //  region
    unsigned short* wb0 = (unsigned short*)(ws + off); off += 51200 * 2;
    unsigned short* wb1 = (unsigned short*)(ws + off); off += 25600 * 2;
    unsigned short* wb2 = (unsigned short*)(ws + off); off += 12800 * 2;

    setup_fill<<<4706, 256, 0, stream>>>(w0, w1, w2, wb0, wb1, wb2, (uint4*)xbp);
    norm_fused<<<8192, 256, 0, stream>>>(vis, rub, kn, qn);
    corr_block<<<512, 512, 0, stream>>>(qn, kn, log_temp, xbp, out);
    conv_tile<2, 32, true><<<512, 256, 0, stream>>>(xbp, wb0, b0, h1p);
    conv_tile<1, 32, true><<<512, 256, 0, stream>>>(h1p, wb1, b1, h2p);
    conv_final_tile<<<512, 256, 0, stream>>>(h2p, wb2, b2, out);
}